// Round 11
// baseline (932.271 us; speedup 1.0000x reference)
//
#include <hip/hip_runtime.h>
#include <math.h>

// Problem constants (fixed by the reference)
#define BN 256     // batch N
#define TT 1000    // timesteps
#define NO 10      // obs dim
#define NS 10      // state dim
#define HID 64     // GRU hidden
#define DIN 20     // NO + NS
#define G3 192     // 3*HID
#define SPB 8      // samples per block (MFMA M=16, rows 8..15 zero-pad)
#define NBLK (BN / SPB)
#define GS 8       // steps per staged group
#define NG 125     // groups
#define C_HALF_LOG2PI -0.918938533204672742f

typedef _Float16 f16x8 __attribute__((ext_vector_type(8)));
typedef float f32x4 __attribute__((ext_vector_type(4)));

__device__ __forceinline__ float rcpf(float x) { return __builtin_amdgcn_rcpf(x); }

// Workgroup barrier WITHOUT the vmcnt(0) drain __syncthreads() emits.
__device__ __forceinline__ void sync_lds() {
    asm volatile("s_waitcnt lgkmcnt(0)\n\ts_barrier" ::: "memory");
}

__device__ __forceinline__ f32x4 mfma16(f16x8 a, f16x8 b, f32x4 c) {
    return __builtin_amdgcn_mfma_f32_16x16x32_f16(a, b, c, 0, 0, 0);
}

// ---------------- Phase 1: GRU recurrence as batched MFMA, 2 waves ---------
// R5/R6/R10 fit: step = content + B(waves); B(8)=1500, B(4)=800 — the
// barrier rendezvous dominates. This round: 2 waves, 8 samples/block
// (32 blocks). Wave w owns units 32w..32w+31 (two 16-col N-tiles): 18 gate
// MFMAs + 2 mv MFMAs; nonlin stays 4 tuples/lane. M rows 8..15 are zero-pad
// (independent rows in D -> harmless). Predicted B(2) ~ 450.
__global__ __attribute__((amdgpu_flat_work_group_size(128, 128)))
void gru_mfma2(const float* __restrict__ Yi, const float* __restrict__ Xh,
               const float* __restrict__ Wi, const float* __restrict__ Wh,
               const float* __restrict__ bi, const float* __restrict__ bh,
               const float* __restrict__ Wmu, const float* __restrict__ Wvar,
               float* __restrict__ mv_out) {
    const int tid = threadIdx.x;
    const int lane = tid & 63;
    const int w = tid >> 6;         // wave 0..1
    const int c = lane & 15;        // D col (unit-in-tile) / A row (sample)
    const int q = lane >> 4;        // quad

    // h in A-layout [sample-row][unit], f16, padded to 72 (144 B rows)
    __shared__ _Float16 hbuf[2][16][72];
    // x staged per group [step][sample-row][dim], padded to 40 (rows 8..15
    // and dims 20..39 stay zero for the K=32 / M=16 pads)
    __shared__ _Float16 xbuf[2][GS][16][40];

    const int base = blockIdx.x * SPB;

    // ---- zero-init LDS (pads must be 0) ----
    {
        int* p = (int*)&hbuf[0][0][0];
        for (int i = tid; i < (int)(sizeof(hbuf) / 4); i += 128) p[i] = 0;
        int* p2 = (int*)&xbuf[0][0][0][0];
        for (int i = tid; i < (int)(sizeof(xbuf) / 4); i += 128) p2[i] = 0;
    }
    sync_lds();

    // ---- B-fragments. B[k][n]: lane holds k=8q+j, n=c. Tiles T=2w,2w+1 ----
    const int uA = 32 * w + c;          // tile A unit column
    const int uB = 32 * w + 16 + c;     // tile B unit column
    f16x8 Ar0, Ar1, Az0, Az1, An0, An1, AIr, AIz, AIn;
    f16x8 Br0, Br1, Bz0, Bz1, Bn0, Bn1, BIr, BIz, BIn;
    f16x8 fM0, fM1;                     // mv: dims 16w+c (valid < 20)
    const int dmv = 16 * w + c;
    const bool mv_ok = (dmv < DIN);
#pragma unroll
    for (int j = 0; j < 8; ++j) {
        const int k0 = 8 * q + j;
        const int k1 = 32 + 8 * q + j;
        Ar0[j] = (_Float16)Wh[k0 * G3 + uA];
        Ar1[j] = (_Float16)Wh[k1 * G3 + uA];
        Az0[j] = (_Float16)Wh[k0 * G3 + 64 + uA];
        Az1[j] = (_Float16)Wh[k1 * G3 + 64 + uA];
        An0[j] = (_Float16)Wh[k0 * G3 + 128 + uA];
        An1[j] = (_Float16)Wh[k1 * G3 + 128 + uA];
        Br0[j] = (_Float16)Wh[k0 * G3 + uB];
        Br1[j] = (_Float16)Wh[k1 * G3 + uB];
        Bz0[j] = (_Float16)Wh[k0 * G3 + 64 + uB];
        Bz1[j] = (_Float16)Wh[k1 * G3 + 64 + uB];
        Bn0[j] = (_Float16)Wh[k0 * G3 + 128 + uB];
        Bn1[j] = (_Float16)Wh[k1 * G3 + 128 + uB];
        AIr[j] = (k0 < DIN) ? (_Float16)Wi[k0 * G3 + uA] : (_Float16)0.0f;
        AIz[j] = (k0 < DIN) ? (_Float16)Wi[k0 * G3 + 64 + uA] : (_Float16)0.0f;
        AIn[j] = (k0 < DIN) ? (_Float16)Wi[k0 * G3 + 128 + uA] : (_Float16)0.0f;
        BIr[j] = (k0 < DIN) ? (_Float16)Wi[k0 * G3 + uB] : (_Float16)0.0f;
        BIz[j] = (k0 < DIN) ? (_Float16)Wi[k0 * G3 + 64 + uB] : (_Float16)0.0f;
        BIn[j] = (k0 < DIN) ? (_Float16)Wi[k0 * G3 + 128 + uB] : (_Float16)0.0f;
        float m0 = 0.0f, m1 = 0.0f;
        if (mv_ok) {
            m0 = (dmv < NS) ? Wmu[k0 * NS + dmv] : Wvar[k0 * NS + (dmv - NS)];
            m1 = (dmv < NS) ? Wmu[k1 * NS + dmv] : Wvar[k1 * NS + (dmv - NS)];
        }
        fM0[j] = (_Float16)m0;
        fM1[j] = (_Float16)m1;
    }
    const float brA = bi[uA] + bh[uA], brB = bi[uB] + bh[uB];
    const float bzA = bi[64 + uA] + bh[64 + uA], bzB = bi[64 + uB] + bh[64 + uB];
    const float bxA = bi[128 + uA], bxB = bi[128 + uB];
    const float bhA = bh[128 + uA], bhB = bh[128 + uB];

    // ---- x staging role: thread -> one (src, sample, step) row ----
    const int sm = tid & 7;             // sample within block
    const int ss = (tid >> 3) & 7;      // step within group
    const float* srow = (tid < 64) ? (Yi + (size_t)(base + sm) * TT * NO)
                                   : (Xh + (size_t)(base + sm) * TT * NS);
    const int k0s = (tid < 64) ? 0 : 10;

    // stage group 0
    {
        const float* rp = srow + (size_t)ss * 10;
#pragma unroll
        for (int e = 0; e < 10; ++e)
            xbuf[0][ss][sm][k0s + e] = (_Float16)rp[e];
    }
    sync_lds();

    float hpA[4] = {0, 0, 0, 0};        // h for tile A units (samples 4q+j)
    float hpB[4] = {0, 0, 0, 0};

#pragma unroll 1
    for (int g = 0; g < NG; ++g) {
        float st[10];
        const bool do_ld = (g + 1 < NG);
        if (do_ld) {
            const float* rp = srow + (size_t)(8 * (g + 1) + ss) * 10;
#pragma unroll
            for (int e = 0; e < 10; ++e) st[e] = rp[e];
        }
#pragma unroll
        for (int s = 0; s < GS; ++s) {
            const int t = 8 * g + s;
            const int p = t & 1;
            // A-frags (shared by this wave's two N-tiles)
            const f16x8 ha0 = *(const f16x8*)&hbuf[p][c][8 * q];
            const f16x8 ha1 = *(const f16x8*)&hbuf[p][c][32 + 8 * q];
            const f16x8 xa  = *(const f16x8*)&xbuf[g & 1][s][c][8 * q];
            // mv first: store scatter drains during the rest of the step
            f32x4 Dmv = {0, 0, 0, 0};
            Dmv = mfma16(ha0, fM0, Dmv);
            Dmv = mfma16(ha1, fM1, Dmv);
            if (t > 0 && mv_ok && q < 2) {
#pragma unroll
                for (int j = 0; j < 4; ++j) {
                    const size_t row = (size_t)(base + 4 * q + j) * TT + (t - 1);
                    mv_out[row * DIN + dmv] = Dmv[j];
                }
            }
            // gate tiles
            f32x4 DrA = {0,0,0,0}, DzA = {0,0,0,0}, DxA = {0,0,0,0}, DhA = {0,0,0,0};
            DrA = mfma16(xa, AIr, DrA);
            DzA = mfma16(xa, AIz, DzA);
            DxA = mfma16(xa, AIn, DxA);
            DrA = mfma16(ha0, Ar0, DrA);
            DzA = mfma16(ha0, Az0, DzA);
            DhA = mfma16(ha0, An0, DhA);
            DrA = mfma16(ha1, Ar1, DrA);
            DzA = mfma16(ha1, Az1, DzA);
            DhA = mfma16(ha1, An1, DhA);
            f32x4 DrB = {0,0,0,0}, DzB = {0,0,0,0}, DxB = {0,0,0,0}, DhB = {0,0,0,0};
            DrB = mfma16(xa, BIr, DrB);
            DzB = mfma16(xa, BIz, DzB);
            DxB = mfma16(xa, BIn, DxB);
            DrB = mfma16(ha0, Br0, DrB);
            DzB = mfma16(ha0, Bz0, DzB);
            DhB = mfma16(ha0, Bn0, DhB);
            DrB = mfma16(ha1, Br1, DrB);
            DzB = mfma16(ha1, Bz1, DzB);
            DhB = mfma16(ha1, Bn1, DhB);
            // nonlinearity + h writeback (valid samples: q<2 -> rows 0..7)
#pragma unroll
            for (int j = 0; j < 4; ++j) {
                {
                    const float ar = DrA[j] + brA;
                    const float az = DzA[j] + bzA;
                    const float ax = DxA[j] + bxA;
                    const float ah = DhA[j] + bhA;
                    const float r = rcpf(1.0f + __expf(-ar));
                    const float z = rcpf(1.0f + __expf(-az));
                    const float pre = fmaf(r, ah, ax);
                    const float e2 = __expf(2.0f * pre);
                    const float nn = 1.0f - 2.0f * rcpf(e2 + 1.0f);
                    const float hn = fmaf(z, hpA[j] - nn, nn);
                    hpA[j] = hn;
                    if (q < 2) hbuf[p ^ 1][4 * q + j][uA] = (_Float16)hn;
                }
                {
                    const float ar = DrB[j] + brB;
                    const float az = DzB[j] + bzB;
                    const float ax = DxB[j] + bxB;
                    const float ah = DhB[j] + bhB;
                    const float r = rcpf(1.0f + __expf(-ar));
                    const float z = rcpf(1.0f + __expf(-az));
                    const float pre = fmaf(r, ah, ax);
                    const float e2 = __expf(2.0f * pre);
                    const float nn = 1.0f - 2.0f * rcpf(e2 + 1.0f);
                    const float hn = fmaf(z, hpB[j] - nn, nn);
                    hpB[j] = hn;
                    if (q < 2) hbuf[p ^ 1][4 * q + j][uB] = (_Float16)hn;
                }
            }
            // stage next group's x just before the group's last barrier
            if (s == GS - 1 && do_ld) {
#pragma unroll
                for (int e = 0; e < 10; ++e)
                    xbuf[(g + 1) & 1][ss][sm][k0s + e] = (_Float16)st[e];
            }
            sync_lds();
        }
    }

    // epilogue: mv of h_999 (t=999 wrote h into hbuf[0]; last barrier done)
    {
        const f16x8 ha0 = *(const f16x8*)&hbuf[0][c][8 * q];
        const f16x8 ha1 = *(const f16x8*)&hbuf[0][c][32 + 8 * q];
        f32x4 Dmv = {0, 0, 0, 0};
        Dmv = mfma16(ha0, fM0, Dmv);
        Dmv = mfma16(ha1, fM1, Dmv);
        if (mv_ok && q < 2) {
#pragma unroll
            for (int j = 0; j < 4; ++j) {
                const size_t row = (size_t)(base + 4 * q + j) * TT + (TT - 1);
                mv_out[row * DIN + dmv] = Dmv[j];
            }
        }
    }
}

// ---------------- Phase 2: per-(n,t) Gaussian log-lik (proven R6 path) -----
__global__ __launch_bounds__(256)
void lik_p2(const float* __restrict__ Yi, const float* __restrict__ Cw,
            const float* __restrict__ Hm, const float* __restrict__ mu_w,
            const float* __restrict__ b_mu, const float* __restrict__ b_var,
            const float* __restrict__ mv_in, float* __restrict__ out) {
    __shared__ float sH[NO * NS];
    __shared__ float smw[NO], sbm[NS], sbv[NS];
    __shared__ float ssum[4];
    const int tid = threadIdx.x;
    if (tid < NO * NS) sH[tid] = Hm[tid];
    if (tid < NO) smw[tid] = mu_w[tid];
    if (tid < NS) { sbm[tid] = b_mu[tid]; sbv[tid] = b_var[tid]; }
    __syncthreads();

    const int gid = blockIdx.x * 256 + tid;   // 0 .. BN*TT-1
    float contrib = 0.0f;
    if (gid < BN * TT) {
        const int n = gid / TT;
        const float* mv = mv_in + (size_t)gid * DIN;
        float mu[NS], va[NS];
#pragma unroll
        for (int i = 0; i < NS; ++i) {
            mu[i] = mv[i] + sbm[i];
            float x = mv[NS + i] + sbv[i];
            va[i] = (x > 0.0f) ? (x + log1pf(__expf(-x))) : log1pf(__expf(x));
        }
        const float* y = Yi + (size_t)gid * NO;
        float e[NO];
#pragma unroll
        for (int i = 0; i < NO; ++i) {
            float m = smw[i];
#pragma unroll
            for (int j = 0; j < NS; ++j) m = fmaf(sH[i * NS + j], mu[j], m);
            e[i] = y[i] - m;
        }
        // M = H diag(va) H^T + Cw (lower triangle only)
        float M[NO][NO];
        const float* cw = Cw + (size_t)n * NO * NO;
#pragma unroll
        for (int i = 0; i < NO; ++i)
#pragma unroll
            for (int j = 0; j <= i; ++j) M[i][j] = cw[i * NO + j];
#pragma unroll
        for (int l = 0; l < NS; ++l) {
            float vl = va[l];
            float hv[NO];
#pragma unroll
            for (int i = 0; i < NO; ++i) hv[i] = sH[i * NS + l];
#pragma unroll
            for (int i = 0; i < NO; ++i) {
                float hvi = hv[i] * vl;
#pragma unroll
                for (int j = 0; j <= i; ++j) M[i][j] = fmaf(hvi, hv[j], M[i][j]);
            }
        }
        // Cholesky; logdet = log(prod d_j); forward solve uses 1/L_jj = rs
        float dprod = 1.0f;
        float drs[NO];
#pragma unroll
        for (int j = 0; j < NO; ++j) {
            float d = M[j][j];
#pragma unroll
            for (int k = 0; k < j; ++k) d = fmaf(-M[j][k], M[j][k], d);
            dprod *= d;
            float rs = __frsqrt_rn(d);
            drs[j] = rs;
#pragma unroll
            for (int i = j + 1; i < NO; ++i) {
                float v = M[i][j];
#pragma unroll
                for (int k = 0; k < j; ++k) v = fmaf(-M[i][k], M[j][k], v);
                M[i][j] = v * rs;
            }
        }
        const float logdet = __logf(dprod);
        float wv[NO];
        float quad = 0.0f;
#pragma unroll
        for (int i = 0; i < NO; ++i) {
            float v = e[i];
#pragma unroll
            for (int k = 0; k < i; ++k) v = fmaf(-M[i][k], wv[k], v);
            wv[i] = v * drs[i];
            quad = fmaf(wv[i], wv[i], quad);
        }
        const float SCALE = 0.5f / ((float)BN * (float)TT * (float)NO);
        contrib = -(logdet + quad) * SCALE;
    }

#pragma unroll
    for (int off = 32; off > 0; off >>= 1) contrib += __shfl_down(contrib, off);
    if ((tid & 63) == 0) ssum[tid >> 6] = contrib;
    __syncthreads();
    if (tid == 0) {
        float s = ssum[0] + ssum[1] + ssum[2] + ssum[3];
        if (blockIdx.x == 0) s += C_HALF_LOG2PI;   // d_out zeroed pre-launch
        atomicAdd(out, s);
    }
}

// ---------------- launch ---------------------------------------------------
extern "C" void kernel_launch(void* const* d_in, const int* in_sizes, int n_in,
                              void* d_out, int out_size, void* d_ws, size_t ws_size,
                              hipStream_t stream) {
    const float* Yi    = (const float*)d_in[0];
    const float* Xh    = (const float*)d_in[1];
    const float* Cw    = (const float*)d_in[2];
    const float* Hm    = (const float*)d_in[3];
    const float* mu_w  = (const float*)d_in[4];
    const float* Wi    = (const float*)d_in[5];
    const float* Wh    = (const float*)d_in[6];
    const float* bi    = (const float*)d_in[7];
    const float* bh    = (const float*)d_in[8];
    const float* W_mu  = (const float*)d_in[9];
    const float* b_mu  = (const float*)d_in[10];
    const float* W_var = (const float*)d_in[11];
    const float* b_var = (const float*)d_in[12];
    float* out = (float*)d_out;
    float* mv  = (float*)d_ws;   // [BN*TT*DIN] floats = 20.48 MB

    hipMemsetAsync(d_out, 0, sizeof(float), stream);
    gru_mfma2<<<dim3(NBLK), dim3(128), 0, stream>>>(Yi, Xh, Wi, Wh, bi, bh,
                                                    W_mu, W_var, mv);
    lik_p2<<<dim3((BN * TT + 255) / 256), dim3(256), 0, stream>>>(
        Yi, Cw, Hm, mu_w, b_mu, b_var, mv, out);
}